// Round 12
// baseline (371.603 us; speedup 1.0000x reference)
//
#include <hip/hip_runtime.h>
#include <hip/hip_fp16.h>

#define EPSF 1e-8f

typedef _Float16 half8 __attribute__((ext_vector_type(8)));
typedef float f32x4 __attribute__((ext_vector_type(4)));

// B=16, L=4096, I=64, H=512, O=1. M = B*L = 65536. CHUNK=64, NC=64.

__device__ __forceinline__ float sigmoidf_(float x) {
    return 1.0f / (1.0f + __expf(-x));
}
__device__ __forceinline__ float tanh_fast(float x) {  // x in (0,1)
    float e = __expf(-2.0f * x);
    return (1.0f - e) / (1.0f + e);
}
// transform pre-activations -> (a, b) of recurrence h = a*h + b
__device__ __forceinline__ void gate_transform(float pz, float ph, float& a, float& b) {
    float k = sigmoidf_(pz);          // k = sigmoid(x@Wz+bz)
    float z = sigmoidf_(k);           // z = sigmoid(k)   (faithful double-sigmoid)
    a = 1.0f - z;                     // exp(-softplus(k))
    float hw = tanh_fast(sigmoidf_(ph)) + EPSF;  // log_g(sigmoid(x@Wh+bh))
    b = z * hw;
}

// async global->LDS, 16B per lane; LDS dest = wave-uniform base + lane*16
__device__ __forceinline__ void gload16(const void* g, void* l) {
    __builtin_amdgcn_global_load_lds(
        (const __attribute__((address_space(1))) unsigned int*)g,
        (__attribute__((address_space(3))) unsigned int*)l, 16, 0, 0);
}

// Ordered affine compose across the 4 q-subgroups of a 64-lane wave.
__device__ __forceinline__ void qscan(int q, float pA, float pB,
                                      float& fA, float& fB, float& prA, float& prB)
{
    float oA = __shfl_xor(pA, 16, 64), oB = __shfl_xor(pB, 16, 64);
    float eA = (q & 1) ? oA : pA, eB = (q & 1) ? oB : pB;   // earlier of pair
    float lA = (q & 1) ? pA : oA, lB = (q & 1) ? pB : oB;   // later of pair
    float p2A = eA * lA;
    float p2B = fmaf(lA, eB, lB);
    float o2A = __shfl_xor(p2A, 32, 64), o2B = __shfl_xor(p2B, 32, 64);
    float loA = (q & 2) ? o2A : p2A, loB = (q & 2) ? o2B : p2B;
    float hiA = (q & 2) ? p2A : o2A, hiB = (q & 2) ? p2B : o2B;
    fA = loA * hiA;
    fB = fmaf(hiA, loB, hiB);
    prA = (q & 2) ? o2A : 1.0f;
    prB = (q & 2) ? o2B : 0.0f;
    if (q & 1) { prB = fmaf(oA, prB, oB); prA *= oA; }
}

// ---------------- kprep: x f32->fp16 (blocks 0..2047) + 4 weight transposes ------
__global__ __launch_bounds__(256) void kprep(
    const float* __restrict__ x, __half* __restrict__ x16,
    const float* __restrict__ Wz1, const float* __restrict__ Wh1,
    __half* __restrict__ Wtz1, __half* __restrict__ Wth1,
    const float* __restrict__ Wz0, const float* __restrict__ Wh0,
    __half* __restrict__ Wtz0, __half* __restrict__ Wth0)
{
    __shared__ float t[64][65];
    const int tid = threadIdx.x;
    int b = blockIdx.x;
    if (b < 2048) {
        const size_t i = ((size_t)(b * 256 + tid)) * 8;
        float4 v0 = *(const float4*)&x[i];
        float4 v1 = *(const float4*)&x[i + 4];
        __half2* o = (__half2*)(x16 + i);
        o[0] = __floats2half2_rn(v0.x, v0.y);
        o[1] = __floats2half2_rn(v0.z, v0.w);
        o[2] = __floats2half2_rn(v1.x, v1.y);
        o[3] = __floats2half2_rn(v1.z, v1.w);
        return;
    }
    b -= 2048;
    const float* W; __half* Wt; int ldt, n0, k0;
    if (b < 64)       { W = Wz1; Wt = Wtz1; ldt = 512; n0 = (b & 7) * 64; k0 = (b >> 3) * 64; }
    else if (b < 128) { b -= 64;  W = Wh1; Wt = Wth1; ldt = 512; n0 = (b & 7) * 64; k0 = (b >> 3) * 64; }
    else if (b < 136) { b -= 128; W = Wz0; Wt = Wtz0; ldt = 64;  n0 = b * 64; k0 = 0; }
    else              { b -= 136; W = Wh0; Wt = Wth0; ldt = 64;  n0 = b * 64; k0 = 0; }
    const int r = tid >> 4, c4 = (tid & 15) * 4;
#pragma unroll
    for (int rr = 0; rr < 64; rr += 16)
        *(float4*)&t[rr + r][c4] = *(const float4*)&W[(size_t)(k0 + rr + r) * 512 + n0 + c4];
    __syncthreads();
#pragma unroll
    for (int rr = 0; rr < 64; rr += 16) {
        const int row = rr + r;
        __half2 h01 = __floats2half2_rn(t[c4 + 0][row], t[c4 + 1][row]);
        __half2 h23 = __floats2half2_rn(t[c4 + 2][row], t[c4 + 3][row]);
        *(__half2*)&Wt[(size_t)(n0 + row) * ldt + k0 + c4] = h01;
        *(__half2*)&Wt[(size_t)(n0 + row) * ldt + k0 + c4 + 2] = h23;
    }
}

// ---------------- k1: layer-0 MFMA GEMM (K=64), BM=128 x BN=64 -------------------
// MODE 0: transform + chunk summaries -> sumA/sumB
// MODE 1: transform + in-register chunk scan with carry-in -> h0 via LDS transpose
// Block 256 thr (4 waves, 2m x 2n), wave tile 64m x 32n x {z,h}. Grid (8, 512).
template<int MODE>
__global__ __launch_bounds__(256) void k1_l0(
    const __half* __restrict__ x16,
    const __half* __restrict__ Wtz, const __half* __restrict__ Wth,  // [512][64] fp16
    const float* __restrict__ bz, const float* __restrict__ bh,
    float* __restrict__ sumA, float* __restrict__ sumB,
    const float* __restrict__ carry, __half* __restrict__ h0)
{
    __shared__ char smem1[32768];
    __half* As = (__half*)smem1;       // [128 rows][64 k] swizzled (16 KB)
    __half* Bs = As + 128 * 64;        // [128 rows][64 k]: rows<64 z, >=64 h (16 KB)
    const int tid = threadIdx.x;
    const int wave = tid >> 6, lane = tid & 63;
    const int q = lane >> 4, l16 = lane & 15;
    const int wm = wave >> 1, wn = wave & 1;

    const int Lb = blockIdx.x + 8 * blockIdx.y;          // 0..4095
    const int lin = (Lb & 7) * 512 + (Lb >> 3);          // bijective XCD swizzle
    const int bx = lin & 7, by = lin >> 3;
    const int m0 = by * 128, n0 = bx * 64;

    {   // stage A (16 regions x 1KB) + B (16 regions); 128B rows, 8 chunks, swz ^(row&7)
        const int r8 = lane >> 3, ch = lane & 7;
#pragma unroll
        for (int i = 0; i < 4; ++i) {
            const int reg = wave * 4 + i;
            const int row = reg * 8 + r8;
            gload16(x16 + (size_t)(m0 + row) * 64 + ((ch ^ (row & 7)) << 3),
                    (char*)As + reg * 1024);
        }
#pragma unroll
        for (int i = 0; i < 4; ++i) {
            const int reg = wave * 4 + i;
            const int row = reg * 8 + r8;
            const __half* src = (row < 64) ? (Wtz + (size_t)(n0 + row) * 64)
                                           : (Wth + (size_t)(n0 + row - 64) * 64);
            gload16(src + ((ch ^ (row & 7)) << 3), (char*)Bs + reg * 1024);
        }
    }
    __syncthreads();

    f32x4 accz[4][2], acch[4][2];
#pragma unroll
    for (int mi = 0; mi < 4; ++mi)
#pragma unroll
        for (int ni = 0; ni < 2; ++ni) {
            accz[mi][ni] = (f32x4){0.f, 0.f, 0.f, 0.f};
            acch[mi][ni] = (f32x4){0.f, 0.f, 0.f, 0.f};
        }

#pragma unroll
    for (int s = 0; s < 2; ++s) {
        half8 af[4];
#pragma unroll
        for (int mi = 0; mi < 4; ++mi) {
            const int row = wm * 64 + mi * 16 + l16;
            const int pc = (s * 4 + q) ^ (row & 7);
            af[mi] = *(const half8*)&As[row * 64 + pc * 8];
        }
#pragma unroll
        for (int ni = 0; ni < 2; ++ni) {
            const int rn = wn * 32 + ni * 16 + l16;           // 0..63
            const int pc = (s * 4 + q) ^ (rn & 7);
            half8 bzf = *(const half8*)&Bs[rn * 64 + pc * 8];
            half8 bhf = *(const half8*)&Bs[(64 + rn) * 64 + pc * 8];
#pragma unroll
            for (int mi = 0; mi < 4; ++mi) {
                accz[mi][ni] = __builtin_amdgcn_mfma_f32_16x16x32_f16(af[mi], bzf, accz[mi][ni], 0, 0, 0);
                acch[mi][ni] = __builtin_amdgcn_mfma_f32_16x16x32_f16(af[mi], bhf, acch[mi][ni], 0, 0, 0);
            }
        }
    }

    // epilogue. C layout: row(m) = q*4 + j (+mi*16), col(n) = l16 (+ni*16)
    const int bidx = by >> 5;                    // 32 m-tiles per batch
    const int chunkg = ((by & 31) << 1) + wm;
    const size_t srow = ((size_t)(bidx * 64 + chunkg)) << 9;

    if (MODE == 1) __syncthreads();    // done reading As/Bs -> overlay h0s
    __half* h0s = (__half*)smem1;      // [128][68] fp16, 17408 B

#pragma unroll
    for (int ni = 0; ni < 2; ++ni) {
        const int colloc = wn * 32 + ni * 16 + l16;           // 0..63
        const int col = n0 + colloc;
        const float bzv = bz[col], bhv = bh[col];
        if (MODE == 0) {
            float fullA = 1.f, fullB = 0.f;
#pragma unroll
            for (int mi = 0; mi < 4; ++mi) {
                float pA = 1.f, pB = 0.f;
#pragma unroll
                for (int j = 0; j < 4; ++j) {
                    float a, b;
                    gate_transform(accz[mi][ni][j] + bzv, acch[mi][ni][j] + bhv, a, b);
                    pB = fmaf(a, pB, b); pA *= a;
                }
                float fA, fB, prA, prB;
                qscan(q, pA, pB, fA, fB, prA, prB);
                fullB = fmaf(fA, fullB, fB); fullA *= fA;
            }
            if (q == 0) { sumA[srow + col] = fullA; sumB[srow + col] = fullB; }
        } else {
            float H = carry[srow + col];
#pragma unroll
            for (int mi = 0; mi < 4; ++mi) {
                float av[4], bv[4];
                float pA = 1.f, pB = 0.f;
#pragma unroll
                for (int j = 0; j < 4; ++j) {
                    gate_transform(accz[mi][ni][j] + bzv, acch[mi][ni][j] + bhv, av[j], bv[j]);
                    pB = fmaf(av[j], pB, bv[j]); pA *= av[j];
                }
                float fA, fB, prA, prB;
                qscan(q, pA, pB, fA, fB, prA, prB);
                float Hl = fmaf(prA, H, prB);        // h before this lane's 4 rows
                const int rloc = wm * 64 + mi * 16 + q * 4;
#pragma unroll
                for (int j = 0; j < 4; ++j) {
                    Hl = fmaf(av[j], Hl, bv[j]);
                    h0s[(rloc + j) * 68 + colloc] = (__half)Hl;
                }
                H = fmaf(fA, H, fB);
            }
        }
    }
    if (MODE == 1) {
        __syncthreads();
        const int row = tid >> 1, cpart = tid & 1;
        const __half* srcp = h0s + row * 68 + cpart * 32;
        __half* dstp = h0 + (size_t)(m0 + row) * 512 + n0 + cpart * 32;
#pragma unroll
        for (int i = 0; i < 4; ++i)
            *(uint4*)(dstp + i * 8) = *(const uint4*)(srcp + i * 8);
    }
}

// ---------------- k2: scan chunk summaries -> per-chunk carry-in ------------------
__global__ __launch_bounds__(256) void k2_carry(
    const float* __restrict__ sumA, const float* __restrict__ sumB,
    float* __restrict__ carry)
{
    const int idx = blockIdx.x * 256 + threadIdx.x;  // 0..8191
    const int b = idx >> 9, h = idx & 511;
    const size_t base = (((size_t)b * 64) << 9) + h;
    float H = EPSF;
#pragma unroll
    for (int c = 0; c < 64; c += 8) {
        float av[8], bv[8];
#pragma unroll
        for (int u = 0; u < 8; ++u) {           // independent loads issue together
            const size_t o = base + ((size_t)(c + u) << 9);
            av[u] = sumA[o]; bv[u] = sumB[o];
        }
#pragma unroll
        for (int u = 0; u < 8; ++u) {
            carry[base + ((size_t)(c + u) << 9)] = H;
            H = fmaf(av[u], H, bv[u]);
        }
    }
}

// ---------------- k4: layer-1 MFMA GEMM (K=512) + transform + chunk summaries -----
// r11 structure (tiles/grid/stage identical, arch VGPR 124) with ONE change:
// counted s_waitcnt vmcnt(6) + raw s_barrier instead of draining __syncthreads.
// Each wave issues exactly 6 gloads per stage; after issuing stage(t+1),
// vmcnt(6) waits precisely for tile t while t+1's loads stay in flight (T4).
// Block 256 thr (4 waves, 2m x 2n), tile 128m x 128n, K_STEP 32, dbuf, grid (4,512).
__global__ __launch_bounds__(256) void k4_l1(
    const __half* __restrict__ h0,
    const __half* __restrict__ Wtz, const __half* __restrict__ Wth,  // [512][512] fp16
    const float* __restrict__ bz, const float* __restrict__ bh,
    float* __restrict__ sumA, float* __restrict__ sumB)
{
    __shared__ __half As[2][128 * 32];   // 8 KB each; 64B rows, 4 chunks, swz ^((row>>1)&3)
    __shared__ __half Bs[2][256 * 32];   // 16 KB each; rows 0..127 z, 128..255 h
    const int tid = threadIdx.x;
    const int wave = tid >> 6, lane = tid & 63;
    const int q = lane >> 4, l16 = lane & 15;
    const int wm = wave >> 1, wn = wave & 1;

    const int Lb = blockIdx.x + 4 * blockIdx.y;
    const int lin = (Lb & 7) * 256 + (Lb >> 3);
    const int bx = lin & 3, by = lin >> 2;
    const int m0 = by * 128, n0 = bx * 128;

    const int r4 = lane >> 2, ch = lane & 3;

    f32x4 accz[4][4], acch[4][4];
#pragma unroll
    for (int mi = 0; mi < 4; ++mi)
#pragma unroll
        for (int ni = 0; ni < 4; ++ni) {
            accz[mi][ni] = (f32x4){0.f, 0.f, 0.f, 0.f};
            acch[mi][ni] = (f32x4){0.f, 0.f, 0.f, 0.f};
        }

    auto stage = [&](int c, int t) {     // 6 gload16 per thread (2 A + 4 B)
#pragma unroll
        for (int i = 0; i < 2; ++i) {          // A: 8 regions x 1KB (16 rows each)
            const int reg = wave * 2 + i;
            const int row = reg * 16 + r4;
            const int pc = ch ^ ((row >> 1) & 3);
            gload16(h0 + (size_t)(m0 + row) * 512 + t * 32 + pc * 8,
                    (char*)&As[c][0] + reg * 1024);
        }
#pragma unroll
        for (int i = 0; i < 4; ++i) {          // B: 16 regions
            const int reg = wave * 4 + i;
            const int row = reg * 16 + r4;
            const int pc = ch ^ ((row >> 1) & 3);
            const __half* src = (row < 128) ? (Wtz + (size_t)(n0 + row) * 512)
                                            : (Wth + (size_t)(n0 + row - 128) * 512);
            gload16(src + t * 32 + pc * 8, (char*)&Bs[c][0] + reg * 1024);
        }
    };

    stage(0, 0);

    int cur = 0;
    for (int t = 0; t < 16; ++t) {
        if (t < 15) {
            stage(cur ^ 1, t + 1);             // issue next tile (6 loads in flight)
            asm volatile("s_waitcnt vmcnt(6)" ::: "memory");   // tile t landed
        } else {
            asm volatile("s_waitcnt vmcnt(0)" ::: "memory");   // drain last tile
        }
        __builtin_amdgcn_s_barrier();          // tile t visible to all waves
        half8 af[4];
#pragma unroll
        for (int mi = 0; mi < 4; ++mi) {
            const int row = wm * 64 + mi * 16 + l16;
            const int pc = q ^ ((row >> 1) & 3);
            af[mi] = *(const half8*)&As[cur][row * 32 + pc * 8];
        }
        __builtin_amdgcn_s_setprio(1);
#pragma unroll
        for (int ni = 0; ni < 4; ++ni) {
            const int rn = wn * 64 + ni * 16 + l16;
            const int pc = q ^ ((rn >> 1) & 3);
            half8 bzf = *(const half8*)&Bs[cur][rn * 32 + pc * 8];
            half8 bhf = *(const half8*)&Bs[cur][(128 + rn) * 32 + pc * 8];
#pragma unroll
            for (int mi = 0; mi < 4; ++mi) {
                accz[mi][ni] = __builtin_amdgcn_mfma_f32_16x16x32_f16(af[mi], bzf, accz[mi][ni], 0, 0, 0);
                acch[mi][ni] = __builtin_amdgcn_mfma_f32_16x16x32_f16(af[mi], bhf, acch[mi][ni], 0, 0, 0);
            }
        }
        __builtin_amdgcn_s_setprio(0);
        __builtin_amdgcn_s_barrier();          // reads of buf cur done (no drain)
        cur ^= 1;
    }

    // epilogue: transform + chunk summary (wave wm owns chunk)
    const int bidx = by >> 5;
    const int chunkg = ((by & 31) << 1) + wm;
    const size_t srow = ((size_t)(bidx * 64 + chunkg)) << 9;
#pragma unroll
    for (int ni = 0; ni < 4; ++ni) {
        const int col = n0 + wn * 64 + ni * 16 + l16;
        const float bzv = bz[col], bhv = bh[col];
        float fullA = 1.f, fullB = 0.f;
#pragma unroll
        for (int mi = 0; mi < 4; ++mi) {
            float pA = 1.f, pB = 0.f;
#pragma unroll
            for (int j = 0; j < 4; ++j) {
                float a, b;
                gate_transform(accz[mi][ni][j] + bzv, acch[mi][ni][j] + bhv, a, b);
                pB = fmaf(a, pB, b); pA *= a;
            }
            float fA, fB, prA, prB;
            qscan(q, pA, pB, fA, fB, prA, prB);
            fullB = fmaf(fA, fullB, fB); fullA *= fA;
        }
        if (q == 0) { sumA[srow + col] = fullA; sumB[srow + col] = fullB; }
    }
}

// ---------------- k5: final chunk scan + GEMV with Wf ----------------------------
__global__ __launch_bounds__(512) void k5_final(
    const float* __restrict__ sumA, const float* __restrict__ sumB,
    const float* __restrict__ Wf, const float* __restrict__ bf,
    float* __restrict__ out)
{
    const int b = blockIdx.x, h = threadIdx.x;
    const size_t base = (((size_t)b * 64) << 9) + h;
    float H = EPSF;
#pragma unroll
    for (int c = 0; c < 64; c += 8) {
        float av[8], bv[8];
#pragma unroll
        for (int u = 0; u < 8; ++u) {
            const size_t o = base + ((size_t)(c + u) << 9);
            av[u] = sumA[o]; bv[u] = sumB[o];
        }
#pragma unroll
        for (int u = 0; u < 8; ++u) H = fmaf(av[u], H, bv[u]);
    }
    float v = H * Wf[h];
#pragma unroll
    for (int off = 32; off; off >>= 1) v += __shfl_down(v, off, 64);
    __shared__ float wsum[8];
    if ((h & 63) == 0) wsum[h >> 6] = v;
    __syncthreads();
    if (h == 0) {
        float s = 0.f;
#pragma unroll
        for (int i = 0; i < 8; ++i) s += wsum[i];
        out[b] = s + bf[0];
    }
}

extern "C" void kernel_launch(void* const* d_in, const int* in_sizes, int n_in,
                              void* d_out, int out_size, void* d_ws, size_t ws_size,
                              hipStream_t stream)
{
    const float* x   = (const float*)d_in[0];
    const float* Wz0 = (const float*)d_in[1];
    const float* bz0 = (const float*)d_in[2];
    const float* Wh0 = (const float*)d_in[3];
    const float* bh0 = (const float*)d_in[4];
    const float* Wz1 = (const float*)d_in[5];
    const float* bz1 = (const float*)d_in[6];
    const float* Wh1 = (const float*)d_in[7];
    const float* bh1 = (const float*)d_in[8];
    const float* Wf  = (const float*)d_in[9];
    const float* bf  = (const float*)d_in[10];
    float* out = (float*)d_out;

    // workspace layout (~80 MiB)
    char* ws = (char*)d_ws;
    __half* x16  = (__half*)ws;                          // 8 MiB
    __half* h0b  = (__half*)(ws + ((size_t)8 << 20));    // 64 MiB
    __half* Wtz1 = (__half*)(ws + ((size_t)72 << 20));   // 512 KiB
    __half* Wth1 = Wtz1 + 262144;                        // 512 KiB
    __half* Wtz0 = Wth1 + 262144;                        // 64 KiB
    __half* Wth0 = Wtz0 + 32768;                         // 64 KiB
    float* sumA  = (float*)(ws + ((size_t)74 << 20));    // 2 MiB
    float* sumB  = sumA + 524288;                        // 2 MiB
    float* carry = sumB + 524288;                        // 2 MiB

    kprep<<<2192, 256, 0, stream>>>(x, x16, Wz1, Wh1, Wtz1, Wth1,
                                    Wz0, Wh0, Wtz0, Wth0);
    k1_l0<0><<<dim3(8, 512), 256, 0, stream>>>(x16, Wtz0, Wth0, bz0, bh0,
                                               sumA, sumB, nullptr, nullptr);
    k2_carry<<<32, 256, 0, stream>>>(sumA, sumB, carry);
    k1_l0<1><<<dim3(8, 512), 256, 0, stream>>>(x16, Wtz0, Wth0, bz0, bh0,
                                               nullptr, nullptr, carry, h0b);
    k4_l1<<<dim3(4, 512), 256, 0, stream>>>(h0b, Wtz1, Wth1, bz1, bh1, sumA, sumB);
    k5_final<<<16, 512, 0, stream>>>(sumA, sumB, Wf, bf, out);
}

// Round 13
// 296.141 us; speedup vs baseline: 1.2548x; 1.2548x over previous
//
#include <hip/hip_runtime.h>
#include <hip/hip_fp16.h>

#define EPSF 1e-8f

typedef _Float16 half8 __attribute__((ext_vector_type(8)));
typedef float f32x4 __attribute__((ext_vector_type(4)));

// B=16, L=4096, I=64, H=512, O=1. M = B*L = 65536. CHUNK=64, NC=64.

__device__ __forceinline__ float sigmoidf_(float x) {
    return 1.0f / (1.0f + __expf(-x));
}
__device__ __forceinline__ float tanh_fast(float x) {  // x in (0,1)
    float e = __expf(-2.0f * x);
    return (1.0f - e) / (1.0f + e);
}
// transform pre-activations -> (a, b) of recurrence h = a*h + b
__device__ __forceinline__ void gate_transform(float pz, float ph, float& a, float& b) {
    float k = sigmoidf_(pz);          // k = sigmoid(x@Wz+bz)
    float z = sigmoidf_(k);           // z = sigmoid(k)   (faithful double-sigmoid)
    a = 1.0f - z;                     // exp(-softplus(k))
    float hw = tanh_fast(sigmoidf_(ph)) + EPSF;  // log_g(sigmoid(x@Wh+bh))
    b = z * hw;
}

// async global->LDS, 16B per lane; LDS dest = wave-uniform base + lane*16
__device__ __forceinline__ void gload16(const void* g, void* l) {
    __builtin_amdgcn_global_load_lds(
        (const __attribute__((address_space(1))) unsigned int*)g,
        (__attribute__((address_space(3))) unsigned int*)l, 16, 0, 0);
}

// Ordered affine compose across the 4 q-subgroups of a 64-lane wave.
__device__ __forceinline__ void qscan(int q, float pA, float pB,
                                      float& fA, float& fB, float& prA, float& prB)
{
    float oA = __shfl_xor(pA, 16, 64), oB = __shfl_xor(pB, 16, 64);
    float eA = (q & 1) ? oA : pA, eB = (q & 1) ? oB : pB;   // earlier of pair
    float lA = (q & 1) ? pA : oA, lB = (q & 1) ? pB : oB;   // later of pair
    float p2A = eA * lA;
    float p2B = fmaf(lA, eB, lB);
    float o2A = __shfl_xor(p2A, 32, 64), o2B = __shfl_xor(p2B, 32, 64);
    float loA = (q & 2) ? o2A : p2A, loB = (q & 2) ? o2B : p2B;
    float hiA = (q & 2) ? p2A : o2A, hiB = (q & 2) ? p2B : o2B;
    fA = loA * hiA;
    fB = fmaf(hiA, loB, hiB);
    prA = (q & 2) ? o2A : 1.0f;
    prB = (q & 2) ? o2B : 0.0f;
    if (q & 1) { prB = fmaf(oA, prB, oB); prA *= oA; }
}

// ---------------- kprep: x f32->fp16 (blocks 0..2047) + 4 weight transposes ------
__global__ __launch_bounds__(256) void kprep(
    const float* __restrict__ x, __half* __restrict__ x16,
    const float* __restrict__ Wz1, const float* __restrict__ Wh1,
    __half* __restrict__ Wtz1, __half* __restrict__ Wth1,
    const float* __restrict__ Wz0, const float* __restrict__ Wh0,
    __half* __restrict__ Wtz0, __half* __restrict__ Wth0)
{
    __shared__ float t[64][65];
    const int tid = threadIdx.x;
    int b = blockIdx.x;
    if (b < 2048) {
        const size_t i = ((size_t)(b * 256 + tid)) * 8;
        float4 v0 = *(const float4*)&x[i];
        float4 v1 = *(const float4*)&x[i + 4];
        __half2* o = (__half2*)(x16 + i);
        o[0] = __floats2half2_rn(v0.x, v0.y);
        o[1] = __floats2half2_rn(v0.z, v0.w);
        o[2] = __floats2half2_rn(v1.x, v1.y);
        o[3] = __floats2half2_rn(v1.z, v1.w);
        return;
    }
    b -= 2048;
    const float* W; __half* Wt; int ldt, n0, k0;
    if (b < 64)       { W = Wz1; Wt = Wtz1; ldt = 512; n0 = (b & 7) * 64; k0 = (b >> 3) * 64; }
    else if (b < 128) { b -= 64;  W = Wh1; Wt = Wth1; ldt = 512; n0 = (b & 7) * 64; k0 = (b >> 3) * 64; }
    else if (b < 136) { b -= 128; W = Wz0; Wt = Wtz0; ldt = 64;  n0 = b * 64; k0 = 0; }
    else              { b -= 136; W = Wh0; Wt = Wth0; ldt = 64;  n0 = b * 64; k0 = 0; }
    const int r = tid >> 4, c4 = (tid & 15) * 4;
#pragma unroll
    for (int rr = 0; rr < 64; rr += 16)
        *(float4*)&t[rr + r][c4] = *(const float4*)&W[(size_t)(k0 + rr + r) * 512 + n0 + c4];
    __syncthreads();
#pragma unroll
    for (int rr = 0; rr < 64; rr += 16) {
        const int row = rr + r;
        __half2 h01 = __floats2half2_rn(t[c4 + 0][row], t[c4 + 1][row]);
        __half2 h23 = __floats2half2_rn(t[c4 + 2][row], t[c4 + 3][row]);
        *(__half2*)&Wt[(size_t)(n0 + row) * ldt + k0 + c4] = h01;
        *(__half2*)&Wt[(size_t)(n0 + row) * ldt + k0 + c4 + 2] = h23;
    }
}

// ---------------- k1: layer-0 MFMA GEMM (K=64), BM=128 x BN=64 -------------------
// MODE 0: transform + chunk summaries -> sumA/sumB
// MODE 1: transform + in-register chunk scan with carry-in -> h0 via LDS transpose
// Block 256 thr (4 waves, 2m x 2n), wave tile 64m x 32n x {z,h}. Grid (8, 512).
template<int MODE>
__global__ __launch_bounds__(256) void k1_l0(
    const __half* __restrict__ x16,
    const __half* __restrict__ Wtz, const __half* __restrict__ Wth,  // [512][64] fp16
    const float* __restrict__ bz, const float* __restrict__ bh,
    float* __restrict__ sumA, float* __restrict__ sumB,
    const float* __restrict__ carry, __half* __restrict__ h0)
{
    __shared__ char smem1[32768];
    __half* As = (__half*)smem1;       // [128 rows][64 k] swizzled (16 KB)
    __half* Bs = As + 128 * 64;        // [128 rows][64 k]: rows<64 z, >=64 h (16 KB)
    const int tid = threadIdx.x;
    const int wave = tid >> 6, lane = tid & 63;
    const int q = lane >> 4, l16 = lane & 15;
    const int wm = wave >> 1, wn = wave & 1;

    const int Lb = blockIdx.x + 8 * blockIdx.y;          // 0..4095
    const int lin = (Lb & 7) * 512 + (Lb >> 3);          // bijective XCD swizzle
    const int bx = lin & 7, by = lin >> 3;
    const int m0 = by * 128, n0 = bx * 64;

    {   // stage A (16 regions x 1KB) + B (16 regions); 128B rows, 8 chunks, swz ^(row&7)
        const int r8 = lane >> 3, ch = lane & 7;
#pragma unroll
        for (int i = 0; i < 4; ++i) {
            const int reg = wave * 4 + i;
            const int row = reg * 8 + r8;
            gload16(x16 + (size_t)(m0 + row) * 64 + ((ch ^ (row & 7)) << 3),
                    (char*)As + reg * 1024);
        }
#pragma unroll
        for (int i = 0; i < 4; ++i) {
            const int reg = wave * 4 + i;
            const int row = reg * 8 + r8;
            const __half* src = (row < 64) ? (Wtz + (size_t)(n0 + row) * 64)
                                           : (Wth + (size_t)(n0 + row - 64) * 64);
            gload16(src + ((ch ^ (row & 7)) << 3), (char*)Bs + reg * 1024);
        }
    }
    __syncthreads();

    f32x4 accz[4][2], acch[4][2];
#pragma unroll
    for (int mi = 0; mi < 4; ++mi)
#pragma unroll
        for (int ni = 0; ni < 2; ++ni) {
            accz[mi][ni] = (f32x4){0.f, 0.f, 0.f, 0.f};
            acch[mi][ni] = (f32x4){0.f, 0.f, 0.f, 0.f};
        }

#pragma unroll
    for (int s = 0; s < 2; ++s) {
        half8 af[4];
#pragma unroll
        for (int mi = 0; mi < 4; ++mi) {
            const int row = wm * 64 + mi * 16 + l16;
            const int pc = (s * 4 + q) ^ (row & 7);
            af[mi] = *(const half8*)&As[row * 64 + pc * 8];
        }
#pragma unroll
        for (int ni = 0; ni < 2; ++ni) {
            const int rn = wn * 32 + ni * 16 + l16;           // 0..63
            const int pc = (s * 4 + q) ^ (rn & 7);
            half8 bzf = *(const half8*)&Bs[rn * 64 + pc * 8];
            half8 bhf = *(const half8*)&Bs[(64 + rn) * 64 + pc * 8];
#pragma unroll
            for (int mi = 0; mi < 4; ++mi) {
                accz[mi][ni] = __builtin_amdgcn_mfma_f32_16x16x32_f16(af[mi], bzf, accz[mi][ni], 0, 0, 0);
                acch[mi][ni] = __builtin_amdgcn_mfma_f32_16x16x32_f16(af[mi], bhf, acch[mi][ni], 0, 0, 0);
            }
        }
    }

    // epilogue. C layout: row(m) = q*4 + j (+mi*16), col(n) = l16 (+ni*16)
    const int bidx = by >> 5;                    // 32 m-tiles per batch
    const int chunkg = ((by & 31) << 1) + wm;
    const size_t srow = ((size_t)(bidx * 64 + chunkg)) << 9;

    if (MODE == 1) __syncthreads();    // done reading As/Bs -> overlay h0s
    __half* h0s = (__half*)smem1;      // [128][68] fp16, 17408 B

#pragma unroll
    for (int ni = 0; ni < 2; ++ni) {
        const int colloc = wn * 32 + ni * 16 + l16;           // 0..63
        const int col = n0 + colloc;
        const float bzv = bz[col], bhv = bh[col];
        if (MODE == 0) {
            float fullA = 1.f, fullB = 0.f;
#pragma unroll
            for (int mi = 0; mi < 4; ++mi) {
                float pA = 1.f, pB = 0.f;
#pragma unroll
                for (int j = 0; j < 4; ++j) {
                    float a, b;
                    gate_transform(accz[mi][ni][j] + bzv, acch[mi][ni][j] + bhv, a, b);
                    pB = fmaf(a, pB, b); pA *= a;
                }
                float fA, fB, prA, prB;
                qscan(q, pA, pB, fA, fB, prA, prB);
                fullB = fmaf(fA, fullB, fB); fullA *= fA;
            }
            if (q == 0) { sumA[srow + col] = fullA; sumB[srow + col] = fullB; }
        } else {
            float H = carry[srow + col];
#pragma unroll
            for (int mi = 0; mi < 4; ++mi) {
                float av[4], bv[4];
                float pA = 1.f, pB = 0.f;
#pragma unroll
                for (int j = 0; j < 4; ++j) {
                    gate_transform(accz[mi][ni][j] + bzv, acch[mi][ni][j] + bhv, av[j], bv[j]);
                    pB = fmaf(av[j], pB, bv[j]); pA *= av[j];
                }
                float fA, fB, prA, prB;
                qscan(q, pA, pB, fA, fB, prA, prB);
                float Hl = fmaf(prA, H, prB);        // h before this lane's 4 rows
                const int rloc = wm * 64 + mi * 16 + q * 4;
#pragma unroll
                for (int j = 0; j < 4; ++j) {
                    Hl = fmaf(av[j], Hl, bv[j]);
                    h0s[(rloc + j) * 68 + colloc] = (__half)Hl;
                }
                H = fmaf(fA, H, fB);
            }
        }
    }
    if (MODE == 1) {
        __syncthreads();
        const int row = tid >> 1, cpart = tid & 1;
        const __half* srcp = h0s + row * 68 + cpart * 32;
        __half* dstp = h0 + (size_t)(m0 + row) * 512 + n0 + cpart * 32;
#pragma unroll
        for (int i = 0; i < 4; ++i)
            *(uint4*)(dstp + i * 8) = *(const uint4*)(srcp + i * 8);
    }
}

// ---------------- k2: scan chunk summaries -> per-chunk carry-in ------------------
__global__ __launch_bounds__(256) void k2_carry(
    const float* __restrict__ sumA, const float* __restrict__ sumB,
    float* __restrict__ carry)
{
    const int idx = blockIdx.x * 256 + threadIdx.x;  // 0..8191
    const int b = idx >> 9, h = idx & 511;
    const size_t base = (((size_t)b * 64) << 9) + h;
    float H = EPSF;
#pragma unroll
    for (int c = 0; c < 64; c += 8) {
        float av[8], bv[8];
#pragma unroll
        for (int u = 0; u < 8; ++u) {           // independent loads issue together
            const size_t o = base + ((size_t)(c + u) << 9);
            av[u] = sumA[o]; bv[u] = sumB[o];
        }
#pragma unroll
        for (int u = 0; u < 8; ++u) {
            carry[base + ((size_t)(c + u) << 9)] = H;
            H = fmaf(av[u], H, bv[u]);
        }
    }
}

// ---------------- k4: layer-1 MFMA GEMM (K=512) + transform + chunk summaries -----
// r11 tiles/stage + counted vmcnt(6) waits, with the r12 register confound removed:
// (a) branch-free main loop (last iteration peeled), (b) __launch_bounds__(256,2)
// pins total regs (VGPR+AGPR unified) <= 256, i.e. arch VGPR <= 128 -> 2 waves/SIMD.
// Block 256 thr (4 waves, 2m x 2n), tile 128m x 128n, K_STEP 32, dbuf, grid (4,512).
__global__ __launch_bounds__(256, 2) void k4_l1(
    const __half* __restrict__ h0,
    const __half* __restrict__ Wtz, const __half* __restrict__ Wth,  // [512][512] fp16
    const float* __restrict__ bz, const float* __restrict__ bh,
    float* __restrict__ sumA, float* __restrict__ sumB)
{
    __shared__ __half As[2][128 * 32];   // 8 KB each; 64B rows, 4 chunks, swz ^((row>>1)&3)
    __shared__ __half Bs[2][256 * 32];   // 16 KB each; rows 0..127 z, 128..255 h
    const int tid = threadIdx.x;
    const int wave = tid >> 6, lane = tid & 63;
    const int q = lane >> 4, l16 = lane & 15;
    const int wm = wave >> 1, wn = wave & 1;

    const int Lb = blockIdx.x + 4 * blockIdx.y;
    const int lin = (Lb & 7) * 256 + (Lb >> 3);
    const int bx = lin & 3, by = lin >> 2;
    const int m0 = by * 128, n0 = bx * 128;

    const int r4 = lane >> 2, ch = lane & 3;

    f32x4 accz[4][4], acch[4][4];
#pragma unroll
    for (int mi = 0; mi < 4; ++mi)
#pragma unroll
        for (int ni = 0; ni < 4; ++ni) {
            accz[mi][ni] = (f32x4){0.f, 0.f, 0.f, 0.f};
            acch[mi][ni] = (f32x4){0.f, 0.f, 0.f, 0.f};
        }

    auto stage = [&](int c, int t) {     // 6 gload16 per thread (2 A + 4 B)
#pragma unroll
        for (int i = 0; i < 2; ++i) {          // A: 8 regions x 1KB (16 rows each)
            const int reg = wave * 2 + i;
            const int row = reg * 16 + r4;
            const int pc = ch ^ ((row >> 1) & 3);
            gload16(h0 + (size_t)(m0 + row) * 512 + t * 32 + pc * 8,
                    (char*)&As[c][0] + reg * 1024);
        }
#pragma unroll
        for (int i = 0; i < 4; ++i) {          // B: 16 regions
            const int reg = wave * 4 + i;
            const int row = reg * 16 + r4;
            const int pc = ch ^ ((row >> 1) & 3);
            const __half* src = (row < 128) ? (Wtz + (size_t)(n0 + row) * 512)
                                            : (Wth + (size_t)(n0 + row - 128) * 512);
            gload16(src + t * 32 + pc * 8, (char*)&Bs[c][0] + reg * 1024);
        }
    };
    auto compute = [&](int c) {
        half8 af[4];
#pragma unroll
        for (int mi = 0; mi < 4; ++mi) {
            const int row = wm * 64 + mi * 16 + l16;
            const int pc = q ^ ((row >> 1) & 3);
            af[mi] = *(const half8*)&As[c][row * 32 + pc * 8];
        }
        __builtin_amdgcn_s_setprio(1);
#pragma unroll
        for (int ni = 0; ni < 4; ++ni) {
            const int rn = wn * 64 + ni * 16 + l16;
            const int pc = q ^ ((rn >> 1) & 3);
            half8 bzf = *(const half8*)&Bs[c][rn * 32 + pc * 8];
            half8 bhf = *(const half8*)&Bs[c][(128 + rn) * 32 + pc * 8];
#pragma unroll
            for (int mi = 0; mi < 4; ++mi) {
                accz[mi][ni] = __builtin_amdgcn_mfma_f32_16x16x32_f16(af[mi], bzf, accz[mi][ni], 0, 0, 0);
                acch[mi][ni] = __builtin_amdgcn_mfma_f32_16x16x32_f16(af[mi], bhf, acch[mi][ni], 0, 0, 0);
            }
        }
        __builtin_amdgcn_s_setprio(0);
    };

    stage(0, 0);

    int cur = 0;
#pragma unroll 1
    for (int t = 0; t < 15; ++t) {             // branch-free steady state
        stage(cur ^ 1, t + 1);                 // issue next tile (6 loads in flight)
        asm volatile("s_waitcnt vmcnt(6)" ::: "memory");   // tile t landed
        __builtin_amdgcn_s_barrier();          // tile t visible to all waves
        compute(cur);
        __builtin_amdgcn_s_barrier();          // reads of buf cur done (no drain)
        cur ^= 1;
    }
    asm volatile("s_waitcnt vmcnt(0)" ::: "memory");       // drain tile 15
    __builtin_amdgcn_s_barrier();
    compute(cur);

    // epilogue: transform + chunk summary (wave wm owns chunk)
    const int bidx = by >> 5;
    const int chunkg = ((by & 31) << 1) + wm;
    const size_t srow = ((size_t)(bidx * 64 + chunkg)) << 9;
#pragma unroll
    for (int ni = 0; ni < 4; ++ni) {
        const int col = n0 + wn * 64 + ni * 16 + l16;
        const float bzv = bz[col], bhv = bh[col];
        float fullA = 1.f, fullB = 0.f;
#pragma unroll
        for (int mi = 0; mi < 4; ++mi) {
            float pA = 1.f, pB = 0.f;
#pragma unroll
            for (int j = 0; j < 4; ++j) {
                float a, b;
                gate_transform(accz[mi][ni][j] + bzv, acch[mi][ni][j] + bhv, a, b);
                pB = fmaf(a, pB, b); pA *= a;
            }
            float fA, fB, prA, prB;
            qscan(q, pA, pB, fA, fB, prA, prB);
            fullB = fmaf(fA, fullB, fB); fullA *= fA;
        }
        if (q == 0) { sumA[srow + col] = fullA; sumB[srow + col] = fullB; }
    }
}

// ---------------- k5: final chunk scan + GEMV with Wf ----------------------------
__global__ __launch_bounds__(512) void k5_final(
    const float* __restrict__ sumA, const float* __restrict__ sumB,
    const float* __restrict__ Wf, const float* __restrict__ bf,
    float* __restrict__ out)
{
    const int b = blockIdx.x, h = threadIdx.x;
    const size_t base = (((size_t)b * 64) << 9) + h;
    float H = EPSF;
#pragma unroll
    for (int c = 0; c < 64; c += 8) {
        float av[8], bv[8];
#pragma unroll
        for (int u = 0; u < 8; ++u) {
            const size_t o = base + ((size_t)(c + u) << 9);
            av[u] = sumA[o]; bv[u] = sumB[o];
        }
#pragma unroll
        for (int u = 0; u < 8; ++u) H = fmaf(av[u], H, bv[u]);
    }
    float v = H * Wf[h];
#pragma unroll
    for (int off = 32; off; off >>= 1) v += __shfl_down(v, off, 64);
    __shared__ float wsum[8];
    if ((h & 63) == 0) wsum[h >> 6] = v;
    __syncthreads();
    if (h == 0) {
        float s = 0.f;
#pragma unroll
        for (int i = 0; i < 8; ++i) s += wsum[i];
        out[b] = s + bf[0];
    }
}

extern "C" void kernel_launch(void* const* d_in, const int* in_sizes, int n_in,
                              void* d_out, int out_size, void* d_ws, size_t ws_size,
                              hipStream_t stream)
{
    const float* x   = (const float*)d_in[0];
    const float* Wz0 = (const float*)d_in[1];
    const float* bz0 = (const float*)d_in[2];
    const float* Wh0 = (const float*)d_in[3];
    const float* bh0 = (const float*)d_in[4];
    const float* Wz1 = (const float*)d_in[5];
    const float* bz1 = (const float*)d_in[6];
    const float* Wh1 = (const float*)d_in[7];
    const float* bh1 = (const float*)d_in[8];
    const float* Wf  = (const float*)d_in[9];
    const float* bf  = (const float*)d_in[10];
    float* out = (float*)d_out;

    // workspace layout (~80 MiB)
    char* ws = (char*)d_ws;
    __half* x16  = (__half*)ws;                          // 8 MiB
    __half* h0b  = (__half*)(ws + ((size_t)8 << 20));    // 64 MiB
    __half* Wtz1 = (__half*)(ws + ((size_t)72 << 20));   // 512 KiB
    __half* Wth1 = Wtz1 + 262144;                        // 512 KiB
    __half* Wtz0 = Wth1 + 262144;                        // 64 KiB
    __half* Wth0 = Wtz0 + 32768;                         // 64 KiB
    float* sumA  = (float*)(ws + ((size_t)74 << 20));    // 2 MiB
    float* sumB  = sumA + 524288;                        // 2 MiB
    float* carry = sumB + 524288;                        // 2 MiB

    kprep<<<2192, 256, 0, stream>>>(x, x16, Wz1, Wh1, Wtz1, Wth1,
                                    Wz0, Wh0, Wtz0, Wth0);
    k1_l0<0><<<dim3(8, 512), 256, 0, stream>>>(x16, Wtz0, Wth0, bz0, bh0,
                                               sumA, sumB, nullptr, nullptr);
    k2_carry<<<32, 256, 0, stream>>>(sumA, sumB, carry);
    k1_l0<1><<<dim3(8, 512), 256, 0, stream>>>(x16, Wtz0, Wth0, bz0, bh0,
                                               nullptr, nullptr, carry, h0b);
    k4_l1<<<dim3(4, 512), 256, 0, stream>>>(h0b, Wtz1, Wth1, bz1, bh1, sumA, sumB);
    k5_final<<<16, 512, 0, stream>>>(sumA, sumB, Wf, bf, out);
}